// Round 4
// baseline (231.627 us; speedup 1.0000x reference)
//
#include <hip/hip_runtime.h>
#include <hip/hip_bf16.h>
#include <math.h>

#define BS 1024
#define D 128
#define NP 100000
#define PROWS 100032              // padded to multiple of 64 (32 zero rows)
#define CH 64                     // proxies per chunk/block
#define NCH (PROWS / CH)          // 1563
#define NSL 64                    // reduction slices
#define LOG2E 1.44269504088896340736f

typedef float f32x4 __attribute__((ext_vector_type(4)));
typedef __bf16 bf16x8 __attribute__((ext_vector_type(8)));
typedef unsigned short u16x8 __attribute__((ext_vector_type(8)));

static __device__ __forceinline__ unsigned short f2bf(float x) {
    unsigned int u = __float_as_uint(x);
    return (unsigned short)((u + 0x7fffu + ((u >> 16) & 1u)) >> 16);  // RNE
}

// ---------- kernel 1: batch -> bf16 A, and d_pos (128 blocks) -------------
__global__ __launch_bounds__(256) void prep_kernel(
    const float* __restrict__ batch, const float* __restrict__ proxies,
    const int* __restrict__ labels, unsigned short* __restrict__ A,
    float* __restrict__ d_pos)
{
    int wave = threadIdx.x >> 6, lane = threadIdx.x & 63;
    int sub = lane >> 5, c = lane & 31;
    int row = blockIdx.x * 8 + wave * 2 + sub;   // 0..1023
    float4 v = *(const float4*)(batch + (size_t)row * D + c * 4);
    float ss = v.x*v.x + v.y*v.y + v.z*v.z + v.w*v.w;
    #pragma unroll
    for (int m = 1; m < 32; m <<= 1) ss += __shfl_xor(ss, m, 64);
    float sc = 3.0f / fmaxf(sqrtf(ss), 1e-12f);
    ushort4 pk;
    pk.x = f2bf(v.x*sc); pk.y = f2bf(v.y*sc);
    pk.z = f2bf(v.z*sc); pk.w = f2bf(v.w*sc);
    *(ushort4*)(A + (size_t)row * D + c * 4) = pk;
    // d_pos in fp32: 18 - 2*(b.p_label)
    int lab = labels[row];
    float4 p4 = *(const float4*)(proxies + (size_t)lab * D + c * 4);
    float ps = p4.x*p4.x + p4.y*p4.y + p4.z*p4.z + p4.w*p4.w;
    #pragma unroll
    for (int m = 1; m < 32; m <<= 1) ps += __shfl_xor(ps, m, 64);
    float psc = 3.0f / fmaxf(sqrtf(ps), 1e-12f);
    float dt = (v.x*sc)*(p4.x*psc) + (v.y*sc)*(p4.y*psc)
             + (v.z*sc)*(p4.z*psc) + (v.w*sc)*(p4.w*psc);
    #pragma unroll
    for (int m = 1; m < 32; m <<= 1) dt += __shfl_xor(dt, m, 64);
    if (c == 0) d_pos[row] = 18.0f - 2.0f * dt;
}

// ---------- kernel 2: fused proxy-norm + GEMM + exp row-sums --------------
// Block = 64 proxies. Staging: 4 threads/row x 32 cols each, normalize fp32
// -> bf16 into XOR-swizzled LDS. Then proxies in M (A-op), batch in N (B-op);
// each wave: 16 groups of 16 batch rows; proxy-sum is in-lane + 2 shuffles.
__global__ __launch_bounds__(256, 6) void main_kernel(
    const float* __restrict__ proxies,
    const unsigned short* __restrict__ Abat,
    float* __restrict__ partials)
{
    __shared__ unsigned short Plds[CH * D];   // 16 KB
    const int tid = threadIdx.x;
    const int lane = tid & 63;
    const int wave = tid >> 6, quad = lane >> 4, l15 = lane & 15;
    const int chunk = blockIdx.x;

    // ---- fused normalize+stage: r = tid>>2 (0..63), q = tid&3 (col 32q..) --
    {
        int r = tid >> 2, q = tid & 3;
        int pidx = chunk * CH + r;
        const float* src = proxies + (size_t)pidx * D + q * 32;
        float4 v[8];
        float ss = 0.f;
        if (pidx < NP) {
            #pragma unroll
            for (int i = 0; i < 8; ++i) {
                v[i] = *(const float4*)(src + i * 4);
                ss += v[i].x*v[i].x + v[i].y*v[i].y + v[i].z*v[i].z + v[i].w*v[i].w;
            }
        } else {
            #pragma unroll
            for (int i = 0; i < 8; ++i) v[i] = make_float4(0.f,0.f,0.f,0.f);
        }
        ss += __shfl_xor(ss, 1, 64);
        ss += __shfl_xor(ss, 2, 64);
        float sc = 3.0f / fmaxf(sqrtf(ss), 1e-12f);
        if (pidx >= NP) sc = 0.0f;
        #pragma unroll
        for (int i2 = 0; i2 < 4; ++i2) {
            int cl = q * 4 + i2;          // 16B chunk index within row
            u16x8 w;
            w[0] = f2bf(v[2*i2].x * sc);   w[1] = f2bf(v[2*i2].y * sc);
            w[2] = f2bf(v[2*i2].z * sc);   w[3] = f2bf(v[2*i2].w * sc);
            w[4] = f2bf(v[2*i2+1].x * sc); w[5] = f2bf(v[2*i2+1].y * sc);
            w[6] = f2bf(v[2*i2+1].z * sc); w[7] = f2bf(v[2*i2+1].w * sc);
            *(u16x8*)((char*)Plds + r * 256 + ((cl ^ (r & 15)) << 4)) = w;
        }
    }
    __syncthreads();

    const float c1 = 2.0f * LOG2E, c0 = -18.0f * LOG2E;
    const int row0 = wave * 256;   // this wave's 256 batch rows (16 groups)
    const unsigned short* ab = Abat + (size_t)(row0 + l15) * D + quad * 8;

    bf16x8 Bf[2][4];
    #pragma unroll
    for (int kk = 0; kk < 4; ++kk) Bf[0][kk] = *(const bf16x8*)(ab + kk * 32);

    #pragma unroll
    for (int g = 0; g < 16; ++g) {
        if (g < 15) {   // prefetch next group's B-frags
            #pragma unroll
            for (int kk = 0; kk < 4; ++kk)
                Bf[(g + 1) & 1][kk] = *(const bf16x8*)(ab + (size_t)(g + 1) * 16 * D + kk * 32);
        }
        f32x4 acc[4];
        #pragma unroll
        for (int m = 0; m < 4; ++m) acc[m] = (f32x4){0.f, 0.f, 0.f, 0.f};
        #pragma unroll
        for (int kk = 0; kk < 4; ++kk) {
            #pragma unroll
            for (int m = 0; m < 4; ++m) {
                int prow = m * 16 + l15;
                int cl = kk * 4 + quad;
                bf16x8 af = *(const bf16x8*)((const char*)Plds + prow * 256 + ((cl ^ l15) << 4));
                acc[m] = __builtin_amdgcn_mfma_f32_16x16x32_bf16(
                    af, Bf[g & 1][kk], acc[m], 0, 0, 0);
            }
        }
        // epilogue: lane's batch col = row0+g*16+l15; 16 proxies in-lane
        float t[4];
        #pragma unroll
        for (int m = 0; m < 4; ++m) {
            float e0 = exp2f(fmaf(acc[m][0], c1, c0));
            float e1 = exp2f(fmaf(acc[m][1], c1, c0));
            float e2 = exp2f(fmaf(acc[m][2], c1, c0));
            float e3 = exp2f(fmaf(acc[m][3], c1, c0));
            t[m] = (e0 + e1) + (e2 + e3);
        }
        float rs = (t[0] + t[1]) + (t[2] + t[3]);
        rs += __shfl_xor(rs, 16, 64);   // combine quads (proxy rows)
        rs += __shfl_xor(rs, 32, 64);
        if (quad == 0)
            partials[(size_t)chunk * BS + row0 + g * 16 + l15] = rs;
    }
}

// ---------- kernel 3a: parallel chunk reduction: 256 blocks --------------
__global__ __launch_bounds__(256) void reduce1_kernel(
    const float* __restrict__ partials, float* __restrict__ partial2)
{
    int sl  = blockIdx.x >> 2;                    // 0..63
    int row = (blockIdx.x & 3) * 256 + threadIdx.x;
    float s = 0.f;
    for (int ci = sl; ci < NCH; ci += NSL)
        s += partials[(size_t)ci * BS + row];
    partial2[(size_t)sl * BS + row] = s;
}

// ---------- kernel 3b: final lse + mean (4 blocks, atomicAdd out) --------
__global__ __launch_bounds__(256) void final_kernel(
    const float* __restrict__ partial2, const float* __restrict__ d_pos,
    float* __restrict__ out)
{
    int row = blockIdx.x * 256 + threadIdx.x;
    float tot = 0.f;
    #pragma unroll 8
    for (int sl = 0; sl < NSL; ++sl)
        tot += partial2[(size_t)sl * BS + row];
    float dp = d_pos[row];
    const float PADC = 32.0f * exp2f(-18.0f * LOG2E);  // zero-pad rows
    float neg = tot - expf(-dp) - PADC;                // drop own column
    float val = dp + logf(fmaxf(neg, 1e-37f));
    #pragma unroll
    for (int m = 1; m < 64; m <<= 1) val += __shfl_xor(val, m, 64);
    __shared__ float red[4];
    if ((threadIdx.x & 63) == 0) red[threadIdx.x >> 6] = val;
    __syncthreads();
    if (threadIdx.x == 0) {
        float v = (red[0] + red[1]) + (red[2] + red[3]);
        atomicAdd(out, v * (1.0f / 1024.0f));
    }
}

extern "C" void kernel_launch(void* const* d_in, const int* in_sizes, int n_in,
                              void* d_out, int out_size, void* d_ws, size_t ws_size,
                              hipStream_t stream) {
    const float* batch   = (const float*)d_in[0];
    const float* proxies = (const float*)d_in[1];
    const int*   labels  = (const int*)d_in[2];
    float* out = (float*)d_out;

    char* ws = (char*)d_ws;
    unsigned short* A  = (unsigned short*)ws;                    //   262,144 B
    float* d_pos       = (float*)(ws + 262144);                  //     4,096 B
    float* partials    = (float*)(ws + 266240);                  // 6,402,048 B
    float* partial2    = (float*)(ws + 6668288);                 //   262,144 B

    hipMemsetAsync(d_out, 0, sizeof(float), stream);
    prep_kernel<<<128, 256, 0, stream>>>(batch, proxies, labels, A, d_pos);
    main_kernel<<<NCH, 256, 0, stream>>>(proxies, A, partials);
    reduce1_kernel<<<NSL * 4, 256, 0, stream>>>(partials, partial2);
    final_kernel<<<4, 256, 0, stream>>>(partial2, d_pos, out);
}

// Round 5
// 153.372 us; speedup vs baseline: 1.5102x; 1.5102x over previous
//
#include <hip/hip_runtime.h>
#include <hip/hip_bf16.h>
#include <math.h>

#define BS 1024
#define D 128
#define NP 100000
#define PROWS 100096              // padded to multiple of 128 (96 zero rows)
#define CH 128                    // proxies per chunk/block
#define NCH (PROWS / CH)          // 782
#define NSL 64                    // reduction slices
#define LOG2E 1.44269504088896340736f

typedef float f32x4 __attribute__((ext_vector_type(4)));
typedef __bf16 bf16x8 __attribute__((ext_vector_type(8)));
typedef unsigned short u16x8 __attribute__((ext_vector_type(8)));

static __device__ __forceinline__ unsigned short f2bf(float x) {
    unsigned int u = __float_as_uint(x);
    return (unsigned short)((u + 0x7fffu + ((u >> 16) & 1u)) >> 16);  // RNE
}

// ---------- kernel 1: batch -> bf16 A, and d_pos (128 blocks) -------------
__global__ __launch_bounds__(256) void prep_kernel(
    const float* __restrict__ batch, const float* __restrict__ proxies,
    const int* __restrict__ labels, unsigned short* __restrict__ A,
    float* __restrict__ d_pos)
{
    int wave = threadIdx.x >> 6, lane = threadIdx.x & 63;
    int sub = lane >> 5, c = lane & 31;
    int row = blockIdx.x * 8 + wave * 2 + sub;   // 0..1023
    float4 v = *(const float4*)(batch + (size_t)row * D + c * 4);
    float ss = v.x*v.x + v.y*v.y + v.z*v.z + v.w*v.w;
    #pragma unroll
    for (int m = 1; m < 32; m <<= 1) ss += __shfl_xor(ss, m, 64);
    float sc = 3.0f / fmaxf(sqrtf(ss), 1e-12f);
    ushort4 pk;
    pk.x = f2bf(v.x*sc); pk.y = f2bf(v.y*sc);
    pk.z = f2bf(v.z*sc); pk.w = f2bf(v.w*sc);
    *(ushort4*)(A + (size_t)row * D + c * 4) = pk;
    // d_pos in fp32: 18 - 2*(b.p_label)
    int lab = labels[row];
    float4 p4 = *(const float4*)(proxies + (size_t)lab * D + c * 4);
    float ps = p4.x*p4.x + p4.y*p4.y + p4.z*p4.z + p4.w*p4.w;
    #pragma unroll
    for (int m = 1; m < 32; m <<= 1) ps += __shfl_xor(ps, m, 64);
    float psc = 3.0f / fmaxf(sqrtf(ps), 1e-12f);
    float dt = (v.x*sc)*(p4.x*psc) + (v.y*sc)*(p4.y*psc)
             + (v.z*sc)*(p4.z*psc) + (v.w*sc)*(p4.w*psc);
    #pragma unroll
    for (int m = 1; m < 32; m <<= 1) dt += __shfl_xor(dt, m, 64);
    if (c == 0) d_pos[row] = 18.0f - 2.0f * dt;
}

// ---------- kernel 2: fused proxy-norm + GEMM + exp row-sums --------------
// Block = 128 proxies. Two-pass spill-free staging: pass 1 accumulates sumsq
// (2 threads/row, 64 floats each, 1 shuffle); pass 2 re-reads (L2-hot),
// scales, packs bf16 into XOR-swizzled LDS. Then proxies in M (A-op), batch
// in N (B-op); each wave: 16 groups of 16 batch rows x 128 proxies.
__global__ __launch_bounds__(256, 3) void main_kernel(
    const float* __restrict__ proxies,
    const unsigned short* __restrict__ Abat,
    float* __restrict__ partials)
{
    __shared__ unsigned short Plds[CH * D];   // 32 KB
    const int tid = threadIdx.x;
    const int lane = tid & 63;
    const int wave = tid >> 6, quad = lane >> 4, l15 = lane & 15;
    const int chunk = blockIdx.x;

    // ---- staging: r = tid>>1 (0..127), h = tid&1 (half-row of 64 floats) --
    {
        int r = tid >> 1, h = tid & 1;
        int pidx = chunk * CH + r;
        const float* src = proxies + (size_t)pidx * D + h * 64;
        float ss = 0.f;
        if (pidx < NP) {
            #pragma unroll
            for (int j = 0; j < 16; ++j) {
                float4 v = *(const float4*)(src + j * 4);
                ss += v.x*v.x + v.y*v.y + v.z*v.z + v.w*v.w;
            }
        }
        ss += __shfl_xor(ss, 1, 64);             // combine the two halves
        float sc = 3.0f / fmaxf(sqrtf(ss), 1e-12f);
        #pragma unroll
        for (int j = 0; j < 8; ++j) {
            u16x8 w = (u16x8){0,0,0,0,0,0,0,0};
            if (pidx < NP) {
                float4 a = *(const float4*)(src + j * 8);      // L2 hit
                float4 b = *(const float4*)(src + j * 8 + 4);
                w[0] = f2bf(a.x*sc); w[1] = f2bf(a.y*sc);
                w[2] = f2bf(a.z*sc); w[3] = f2bf(a.w*sc);
                w[4] = f2bf(b.x*sc); w[5] = f2bf(b.y*sc);
                w[6] = f2bf(b.z*sc); w[7] = f2bf(b.w*sc);
            }
            int cl = h * 8 + j;                  // 16B chunk index in row
            *(u16x8*)((char*)Plds + r * 256 + ((cl ^ (r & 15)) << 4)) = w;
        }
    }
    __syncthreads();

    const float c1 = 2.0f * LOG2E, c0 = -18.0f * LOG2E;
    const int row0 = wave * 256;   // this wave's 256 batch rows (16 groups)
    const unsigned short* ab = Abat + (size_t)(row0 + l15) * D + quad * 8;

    bf16x8 Bf[2][4];
    #pragma unroll
    for (int kk = 0; kk < 4; ++kk) Bf[0][kk] = *(const bf16x8*)(ab + kk * 32);

    #pragma unroll
    for (int g = 0; g < 16; ++g) {
        if (g < 15) {   // prefetch next group's B-frags
            #pragma unroll
            for (int kk = 0; kk < 4; ++kk)
                Bf[(g + 1) & 1][kk] = *(const bf16x8*)(ab + (size_t)(g + 1) * 16 * D + kk * 32);
        }
        f32x4 acc[8];
        #pragma unroll
        for (int m = 0; m < 8; ++m) acc[m] = (f32x4){0.f, 0.f, 0.f, 0.f};
        #pragma unroll
        for (int kk = 0; kk < 4; ++kk) {
            #pragma unroll
            for (int m = 0; m < 8; ++m) {
                int prow = m * 16 + l15;
                int cl = kk * 4 + quad;
                bf16x8 af = *(const bf16x8*)((const char*)Plds + prow * 256 + ((cl ^ l15) << 4));
                acc[m] = __builtin_amdgcn_mfma_f32_16x16x32_bf16(
                    af, Bf[g & 1][kk], acc[m], 0, 0, 0);
            }
        }
        // epilogue: lane's batch col = row0+g*16+l15; 32 proxies in-lane
        float rs = 0.f;
        #pragma unroll
        for (int m = 0; m < 8; ++m) {
            float e0 = exp2f(fmaf(acc[m][0], c1, c0));
            float e1 = exp2f(fmaf(acc[m][1], c1, c0));
            float e2 = exp2f(fmaf(acc[m][2], c1, c0));
            float e3 = exp2f(fmaf(acc[m][3], c1, c0));
            rs += (e0 + e1) + (e2 + e3);
        }
        rs += __shfl_xor(rs, 16, 64);   // combine quads (proxy rows)
        rs += __shfl_xor(rs, 32, 64);
        if (quad == 0)
            partials[(size_t)chunk * BS + row0 + g * 16 + l15] = rs;
    }
}

// ---------- kernel 3a: parallel chunk reduction: 256 blocks --------------
__global__ __launch_bounds__(256) void reduce1_kernel(
    const float* __restrict__ partials, float* __restrict__ partial2)
{
    int sl  = blockIdx.x >> 2;                    // 0..63
    int row = (blockIdx.x & 3) * 256 + threadIdx.x;
    float s = 0.f;
    for (int ci = sl; ci < NCH; ci += NSL)
        s += partials[(size_t)ci * BS + row];
    partial2[(size_t)sl * BS + row] = s;
}

// ---------- kernel 3b: final lse + mean (4 blocks, atomicAdd out) --------
__global__ __launch_bounds__(256) void final_kernel(
    const float* __restrict__ partial2, const float* __restrict__ d_pos,
    float* __restrict__ out)
{
    int row = blockIdx.x * 256 + threadIdx.x;
    float tot = 0.f;
    #pragma unroll 8
    for (int sl = 0; sl < NSL; ++sl)
        tot += partial2[(size_t)sl * BS + row];
    float dp = d_pos[row];
    const float PADC = 96.0f * exp2f(-18.0f * LOG2E);  // zero-pad rows
    float neg = tot - expf(-dp) - PADC;                // drop own column
    float val = dp + logf(fmaxf(neg, 1e-37f));
    #pragma unroll
    for (int m = 1; m < 64; m <<= 1) val += __shfl_xor(val, m, 64);
    __shared__ float red[4];
    if ((threadIdx.x & 63) == 0) red[threadIdx.x >> 6] = val;
    __syncthreads();
    if (threadIdx.x == 0) {
        float v = (red[0] + red[1]) + (red[2] + red[3]);
        atomicAdd(out, v * (1.0f / 1024.0f));
    }
}

extern "C" void kernel_launch(void* const* d_in, const int* in_sizes, int n_in,
                              void* d_out, int out_size, void* d_ws, size_t ws_size,
                              hipStream_t stream) {
    const float* batch   = (const float*)d_in[0];
    const float* proxies = (const float*)d_in[1];
    const int*   labels  = (const int*)d_in[2];
    float* out = (float*)d_out;

    char* ws = (char*)d_ws;
    unsigned short* A  = (unsigned short*)ws;                    //   262,144 B
    float* d_pos       = (float*)(ws + 262144);                  //     4,096 B
    float* partials    = (float*)(ws + 266240);                  // 3,203,072 B
    float* partial2    = (float*)(ws + 3469312);                 //   262,144 B

    hipMemsetAsync(d_out, 0, sizeof(float), stream);
    prep_kernel<<<128, 256, 0, stream>>>(batch, proxies, labels, A, d_pos);
    main_kernel<<<NCH, 256, 0, stream>>>(proxies, A, partials);
    reduce1_kernel<<<NSL * 4, 256, 0, stream>>>(partials, partial2);
    final_kernel<<<4, 256, 0, stream>>>(partial2, d_pos, out);
}

// Round 6
// 145.516 us; speedup vs baseline: 1.5918x; 1.0540x over previous
//
#include <hip/hip_runtime.h>
#include <hip/hip_bf16.h>
#include <math.h>

#define BS 1024
#define D 128
#define NP 100000
#define PROWS 100096              // padded to multiple of 128 (96 zero rows)
#define CH 128                    // proxies per chunk/block
#define NCH (PROWS / CH)          // 782
#define LOG2E 1.44269504088896340736f

typedef float f32x4 __attribute__((ext_vector_type(4)));
typedef __bf16 bf16x8 __attribute__((ext_vector_type(8)));
typedef unsigned short u16x8 __attribute__((ext_vector_type(8)));

static __device__ __forceinline__ unsigned short f2bf(float x) {
    unsigned int u = __float_as_uint(x);
    return (unsigned short)((u + 0x7fffu + ((u >> 16) & 1u)) >> 16);  // RNE
}

// ---------- kernel 1: batch -> bf16 A, d_pos; also zero rowsum/out --------
__global__ __launch_bounds__(256) void prep_kernel(
    const float* __restrict__ batch, const float* __restrict__ proxies,
    const int* __restrict__ labels, unsigned short* __restrict__ A,
    float* __restrict__ d_pos, float* __restrict__ rowsum,
    float* __restrict__ out)
{
    // zero the accumulators main/final will atomically update
    if (threadIdx.x < 8) rowsum[blockIdx.x * 8 + threadIdx.x] = 0.f;
    if (blockIdx.x == 0 && threadIdx.x == 0) out[0] = 0.f;

    int wave = threadIdx.x >> 6, lane = threadIdx.x & 63;
    int sub = lane >> 5, c = lane & 31;
    int row = blockIdx.x * 8 + wave * 2 + sub;   // 0..1023
    float4 v = *(const float4*)(batch + (size_t)row * D + c * 4);
    float ss = v.x*v.x + v.y*v.y + v.z*v.z + v.w*v.w;
    #pragma unroll
    for (int m = 1; m < 32; m <<= 1) ss += __shfl_xor(ss, m, 64);
    float sc = 3.0f / fmaxf(sqrtf(ss), 1e-12f);
    ushort4 pk;
    pk.x = f2bf(v.x*sc); pk.y = f2bf(v.y*sc);
    pk.z = f2bf(v.z*sc); pk.w = f2bf(v.w*sc);
    *(ushort4*)(A + (size_t)row * D + c * 4) = pk;
    // d_pos in fp32: 18 - 2*(b.p_label)
    int lab = labels[row];
    float4 p4 = *(const float4*)(proxies + (size_t)lab * D + c * 4);
    float ps = p4.x*p4.x + p4.y*p4.y + p4.z*p4.z + p4.w*p4.w;
    #pragma unroll
    for (int m = 1; m < 32; m <<= 1) ps += __shfl_xor(ps, m, 64);
    float psc = 3.0f / fmaxf(sqrtf(ps), 1e-12f);
    float dt = (v.x*sc)*(p4.x*psc) + (v.y*sc)*(p4.y*psc)
             + (v.z*sc)*(p4.z*psc) + (v.w*sc)*(p4.w*psc);
    #pragma unroll
    for (int m = 1; m < 32; m <<= 1) dt += __shfl_xor(dt, m, 64);
    if (c == 0) d_pos[row] = 18.0f - 2.0f * dt;
}

// ---------- kernel 2: fused proxy-norm + GEMM + exp row-sums --------------
// 512 threads (8 waves), block = 128 proxies. Two-pass spill-free staging
// (4 threads/row). Each wave: 8 groups of 16 batch rows x 128 proxies;
// per-row sums atomicAdd'ed into rowsum[1024].
__global__ __launch_bounds__(512, 6) void main_kernel(
    const float* __restrict__ proxies,
    const unsigned short* __restrict__ Abat,
    float* __restrict__ rowsum)
{
    __shared__ unsigned short Plds[CH * D];   // 32 KB
    const int tid = threadIdx.x;
    const int lane = tid & 63;
    const int wave = tid >> 6, quad = lane >> 4, l15 = lane & 15;
    const int chunk = blockIdx.x;

    // ---- staging: r = tid>>2 (0..127), q = tid&3 (32 floats each) --------
    {
        int r = tid >> 2, q = tid & 3;
        int pidx = chunk * CH + r;
        const float* src = proxies + (size_t)pidx * D + q * 32;
        float ss = 0.f;
        if (pidx < NP) {
            #pragma unroll
            for (int j = 0; j < 8; ++j) {
                float4 v = *(const float4*)(src + j * 4);
                ss += v.x*v.x + v.y*v.y + v.z*v.z + v.w*v.w;
            }
        }
        ss += __shfl_xor(ss, 1, 64);             // combine 4 quarters
        ss += __shfl_xor(ss, 2, 64);
        float sc = 3.0f / fmaxf(sqrtf(ss), 1e-12f);
        #pragma unroll
        for (int i2 = 0; i2 < 4; ++i2) {
            u16x8 w = (u16x8){0,0,0,0,0,0,0,0};
            if (pidx < NP) {
                float4 a = *(const float4*)(src + i2 * 8);      // L2 hit
                float4 b = *(const float4*)(src + i2 * 8 + 4);
                w[0] = f2bf(a.x*sc); w[1] = f2bf(a.y*sc);
                w[2] = f2bf(a.z*sc); w[3] = f2bf(a.w*sc);
                w[4] = f2bf(b.x*sc); w[5] = f2bf(b.y*sc);
                w[6] = f2bf(b.z*sc); w[7] = f2bf(b.w*sc);
            }
            int cl = q * 4 + i2;                 // 16B chunk index in row
            *(u16x8*)((char*)Plds + r * 256 + ((cl ^ (r & 15)) << 4)) = w;
        }
    }
    __syncthreads();

    const float c1 = 2.0f * LOG2E, c0 = -18.0f * LOG2E;
    const int row0 = wave * 128;   // this wave's 128 batch rows (8 groups)
    const unsigned short* ab = Abat + (size_t)(row0 + l15) * D + quad * 8;

    bf16x8 Bf[2][4];
    #pragma unroll
    for (int kk = 0; kk < 4; ++kk) Bf[0][kk] = *(const bf16x8*)(ab + kk * 32);

    #pragma unroll
    for (int g = 0; g < 8; ++g) {
        if (g < 7) {   // prefetch next group's B-frags
            #pragma unroll
            for (int kk = 0; kk < 4; ++kk)
                Bf[(g + 1) & 1][kk] = *(const bf16x8*)(ab + (size_t)(g + 1) * 16 * D + kk * 32);
        }
        f32x4 acc[8];
        #pragma unroll
        for (int m = 0; m < 8; ++m) acc[m] = (f32x4){0.f, 0.f, 0.f, 0.f};
        #pragma unroll
        for (int kk = 0; kk < 4; ++kk) {
            #pragma unroll
            for (int m = 0; m < 8; ++m) {
                int prow = m * 16 + l15;
                int cl = kk * 4 + quad;
                bf16x8 af = *(const bf16x8*)((const char*)Plds + prow * 256 + ((cl ^ l15) << 4));
                acc[m] = __builtin_amdgcn_mfma_f32_16x16x32_bf16(
                    af, Bf[g & 1][kk], acc[m], 0, 0, 0);
            }
        }
        // epilogue: lane's batch col = row0+g*16+l15; 32 proxies in-lane
        float rs = 0.f;
        #pragma unroll
        for (int m = 0; m < 8; ++m) {
            float e0 = exp2f(fmaf(acc[m][0], c1, c0));
            float e1 = exp2f(fmaf(acc[m][1], c1, c0));
            float e2 = exp2f(fmaf(acc[m][2], c1, c0));
            float e3 = exp2f(fmaf(acc[m][3], c1, c0));
            rs += (e0 + e1) + (e2 + e3);
        }
        rs += __shfl_xor(rs, 16, 64);   // combine quads (proxy rows)
        rs += __shfl_xor(rs, 32, 64);
        if (quad == 0)
            atomicAdd(rowsum + row0 + g * 16 + l15, rs);
    }
}

// ---------- kernel 3: final lse + mean (4 blocks, atomicAdd out) ----------
__global__ __launch_bounds__(256) void final_kernel(
    const float* __restrict__ rowsum, const float* __restrict__ d_pos,
    float* __restrict__ out)
{
    int row = blockIdx.x * 256 + threadIdx.x;
    float tot = rowsum[row];
    float dp = d_pos[row];
    const float PADC = 96.0f * exp2f(-18.0f * LOG2E);  // zero-pad rows
    float neg = tot - expf(-dp) - PADC;                // drop own column
    float val = dp + logf(fmaxf(neg, 1e-37f));
    #pragma unroll
    for (int m = 1; m < 64; m <<= 1) val += __shfl_xor(val, m, 64);
    __shared__ float red[4];
    if ((threadIdx.x & 63) == 0) red[threadIdx.x >> 6] = val;
    __syncthreads();
    if (threadIdx.x == 0) {
        float v = (red[0] + red[1]) + (red[2] + red[3]);
        atomicAdd(out, v * (1.0f / 1024.0f));
    }
}

extern "C" void kernel_launch(void* const* d_in, const int* in_sizes, int n_in,
                              void* d_out, int out_size, void* d_ws, size_t ws_size,
                              hipStream_t stream) {
    const float* batch   = (const float*)d_in[0];
    const float* proxies = (const float*)d_in[1];
    const int*   labels  = (const int*)d_in[2];
    float* out = (float*)d_out;

    char* ws = (char*)d_ws;
    unsigned short* A  = (unsigned short*)ws;                    //   262,144 B
    float* d_pos       = (float*)(ws + 262144);                  //     4,096 B
    float* rowsum      = (float*)(ws + 266240);                  //     4,096 B

    prep_kernel<<<128, 256, 0, stream>>>(batch, proxies, labels, A, d_pos, rowsum, out);
    main_kernel<<<NCH, 512, 0, stream>>>(proxies, A, rowsum);
    final_kernel<<<4, 256, 0, stream>>>(rowsum, d_pos, out);
}

// Round 7
// 137.534 us; speedup vs baseline: 1.6841x; 1.0580x over previous
//
#include <hip/hip_runtime.h>
#include <hip/hip_bf16.h>
#include <math.h>

#define BS 1024
#define D 128
#define NP 100000
#define PROWS 100096              // padded to multiple of 128 (96 zero rows)
#define CH 128                    // proxies per chunk/block
#define NCH (PROWS / CH)          // 782
#define NSLICE 16                 // rowsum slices (atomic contention / 16)
#define LOG2E 1.44269504088896340736f

typedef float f32x4 __attribute__((ext_vector_type(4)));
typedef __bf16 bf16x8 __attribute__((ext_vector_type(8)));
typedef unsigned short u16x8 __attribute__((ext_vector_type(8)));

#if defined(__has_builtin)
#if __has_builtin(__builtin_amdgcn_exp2f)
#define FAST_EXP2(x) __builtin_amdgcn_exp2f(x)
#endif
#endif
#ifndef FAST_EXP2
#define FAST_EXP2(x) exp2f(x)
#endif

static __device__ __forceinline__ unsigned short f2bf(float x) {
    unsigned int u = __float_as_uint(x);
    return (unsigned short)((u + 0x7fffu + ((u >> 16) & 1u)) >> 16);  // RNE
}

// ---------- kernel 1: batch -> bf16 A, d_pos; zero rowsum slices + out ----
__global__ __launch_bounds__(256) void prep_kernel(
    const float* __restrict__ batch, const float* __restrict__ proxies,
    const int* __restrict__ labels, unsigned short* __restrict__ A,
    float* __restrict__ d_pos, float* __restrict__ rowsum,
    float* __restrict__ out)
{
    // zero the 16x1024 rowsum slices (128 blocks x 128 entries)
    if (threadIdx.x < 128) rowsum[blockIdx.x * 128 + threadIdx.x] = 0.f;
    if (blockIdx.x == 0 && threadIdx.x == 0) out[0] = 0.f;

    int wave = threadIdx.x >> 6, lane = threadIdx.x & 63;
    int sub = lane >> 5, c = lane & 31;
    int row = blockIdx.x * 8 + wave * 2 + sub;   // 0..1023
    float4 v = *(const float4*)(batch + (size_t)row * D + c * 4);
    float ss = v.x*v.x + v.y*v.y + v.z*v.z + v.w*v.w;
    #pragma unroll
    for (int m = 1; m < 32; m <<= 1) ss += __shfl_xor(ss, m, 64);
    float sc = 3.0f / fmaxf(sqrtf(ss), 1e-12f);
    ushort4 pk;
    pk.x = f2bf(v.x*sc); pk.y = f2bf(v.y*sc);
    pk.z = f2bf(v.z*sc); pk.w = f2bf(v.w*sc);
    *(ushort4*)(A + (size_t)row * D + c * 4) = pk;
    // d_pos in fp32: 18 - 2*(b.p_label)
    int lab = labels[row];
    float4 p4 = *(const float4*)(proxies + (size_t)lab * D + c * 4);
    float ps = p4.x*p4.x + p4.y*p4.y + p4.z*p4.z + p4.w*p4.w;
    #pragma unroll
    for (int m = 1; m < 32; m <<= 1) ps += __shfl_xor(ps, m, 64);
    float psc = 3.0f / fmaxf(sqrtf(ps), 1e-12f);
    float dt = (v.x*sc)*(p4.x*psc) + (v.y*sc)*(p4.y*psc)
             + (v.z*sc)*(p4.z*psc) + (v.w*sc)*(p4.w*psc);
    #pragma unroll
    for (int m = 1; m < 32; m <<= 1) dt += __shfl_xor(dt, m, 64);
    if (c == 0) d_pos[row] = 18.0f - 2.0f * dt;
}

// ---------- kernel 2: fused proxy-norm + GEMM + exp row-sums --------------
// 512 threads (8 waves), block = 128 proxies. Two-pass spill-free staging
// into XOR-swizzled LDS, then the FULL A-operand (128 proxies x 128 K) is
// register-cached per wave: Af[8][4] = 128 VGPRs, loaded from LDS ONCE.
// launch_bounds(512,2) -> 256-reg budget so the cache is not spilled.
// Inner loop per wave: 8 groups of 16 batch rows; only global B-frag loads
// (L2-resident A matrix) + MFMA + exp epilogue. No LDS, no addr VALU.
__global__ __launch_bounds__(512, 2) void main_kernel(
    const float* __restrict__ proxies,
    const unsigned short* __restrict__ Abat,
    float* __restrict__ rowsum)          // [NSLICE][BS]
{
    __shared__ unsigned short Plds[CH * D];   // 32 KB
    const int tid = threadIdx.x;
    const int lane = tid & 63;
    const int wave = tid >> 6, quad = lane >> 4, l15 = lane & 15;
    const int chunk = blockIdx.x;

    // ---- staging: r = tid>>2 (0..127), q = tid&3 (32 floats each) --------
    {
        int r = tid >> 2, q = tid & 3;
        int pidx = chunk * CH + r;
        const float* src = proxies + (size_t)pidx * D + q * 32;
        float ss = 0.f;
        if (pidx < NP) {
            #pragma unroll
            for (int j = 0; j < 8; ++j) {
                float4 v = *(const float4*)(src + j * 4);
                ss += v.x*v.x + v.y*v.y + v.z*v.z + v.w*v.w;
            }
        }
        ss += __shfl_xor(ss, 1, 64);             // combine 4 quarters
        ss += __shfl_xor(ss, 2, 64);
        float sc = 3.0f / fmaxf(sqrtf(ss), 1e-12f);
        #pragma unroll
        for (int i2 = 0; i2 < 4; ++i2) {
            u16x8 w = (u16x8){0,0,0,0,0,0,0,0};
            if (pidx < NP) {
                float4 a = *(const float4*)(src + i2 * 8);      // L2 hit
                float4 b = *(const float4*)(src + i2 * 8 + 4);
                w[0] = f2bf(a.x*sc); w[1] = f2bf(a.y*sc);
                w[2] = f2bf(a.z*sc); w[3] = f2bf(a.w*sc);
                w[4] = f2bf(b.x*sc); w[5] = f2bf(b.y*sc);
                w[6] = f2bf(b.z*sc); w[7] = f2bf(b.w*sc);
            }
            int cl = q * 4 + i2;                 // 16B chunk index in row
            *(u16x8*)((char*)Plds + r * 256 + ((cl ^ (r & 15)) << 4)) = w;
        }
    }
    __syncthreads();

    // ---- register-cache the whole A-operand: one LDS pass, 128 VGPRs -----
    bf16x8 Af[8][4];
    #pragma unroll
    for (int m = 0; m < 8; ++m) {
        #pragma unroll
        for (int kk = 0; kk < 4; ++kk) {
            int prow = m * 16 + l15;
            int cl = kk * 4 + quad;
            Af[m][kk] = *(const bf16x8*)((const char*)Plds + prow * 256 + ((cl ^ l15) << 4));
        }
    }

    const float c1 = 2.0f * LOG2E, c0 = -18.0f * LOG2E;
    const int row0 = wave * 128;   // this wave's 128 batch rows (8 groups)
    const unsigned short* ab = Abat + (size_t)(row0 + l15) * D + quad * 8;

    bf16x8 Bf[2][4];
    #pragma unroll
    for (int kk = 0; kk < 4; ++kk) Bf[0][kk] = *(const bf16x8*)(ab + kk * 32);

    float* rs_base = rowsum + (size_t)(chunk & (NSLICE - 1)) * BS;

    #pragma unroll
    for (int g = 0; g < 8; ++g) {
        if (g < 7) {   // prefetch next group's B-frags (L2-resident)
            #pragma unroll
            for (int kk = 0; kk < 4; ++kk)
                Bf[(g + 1) & 1][kk] = *(const bf16x8*)(ab + (size_t)(g + 1) * 16 * D + kk * 32);
        }
        f32x4 acc[8];
        #pragma unroll
        for (int m = 0; m < 8; ++m) acc[m] = (f32x4){0.f, 0.f, 0.f, 0.f};
        #pragma unroll
        for (int kk = 0; kk < 4; ++kk) {
            #pragma unroll
            for (int m = 0; m < 8; ++m)
                acc[m] = __builtin_amdgcn_mfma_f32_16x16x32_bf16(
                    Af[m][kk], Bf[g & 1][kk], acc[m], 0, 0, 0);
        }
        // epilogue: lane's batch col = row0+g*16+l15; 32 proxies in-lane
        float rs = 0.f;
        #pragma unroll
        for (int m = 0; m < 8; ++m) {
            float e0 = FAST_EXP2(fmaf(acc[m][0], c1, c0));
            float e1 = FAST_EXP2(fmaf(acc[m][1], c1, c0));
            float e2 = FAST_EXP2(fmaf(acc[m][2], c1, c0));
            float e3 = FAST_EXP2(fmaf(acc[m][3], c1, c0));
            rs += (e0 + e1) + (e2 + e3);
        }
        rs += __shfl_xor(rs, 16, 64);   // combine quads (proxy rows)
        rs += __shfl_xor(rs, 32, 64);
        if (quad == 0)
            atomicAdd(rs_base + row0 + g * 16 + l15, rs);
    }
}

// ---------- kernel 3: final lse + mean (4 blocks, atomicAdd out) ----------
__global__ __launch_bounds__(256) void final_kernel(
    const float* __restrict__ rowsum, const float* __restrict__ d_pos,
    float* __restrict__ out)
{
    int row = blockIdx.x * 256 + threadIdx.x;
    float tot = 0.f;
    #pragma unroll
    for (int s = 0; s < NSLICE; ++s)
        tot += rowsum[(size_t)s * BS + row];
    float dp = d_pos[row];
    const float PADC = 96.0f * exp2f(-18.0f * LOG2E);  // zero-pad rows
    float neg = tot - expf(-dp) - PADC;                // drop own column
    float val = dp + logf(fmaxf(neg, 1e-37f));
    #pragma unroll
    for (int m = 1; m < 64; m <<= 1) val += __shfl_xor(val, m, 64);
    __shared__ float red[4];
    if ((threadIdx.x & 63) == 0) red[threadIdx.x >> 6] = val;
    __syncthreads();
    if (threadIdx.x == 0) {
        float v = (red[0] + red[1]) + (red[2] + red[3]);
        atomicAdd(out, v * (1.0f / 1024.0f));
    }
}

extern "C" void kernel_launch(void* const* d_in, const int* in_sizes, int n_in,
                              void* d_out, int out_size, void* d_ws, size_t ws_size,
                              hipStream_t stream) {
    const float* batch   = (const float*)d_in[0];
    const float* proxies = (const float*)d_in[1];
    const int*   labels  = (const int*)d_in[2];
    float* out = (float*)d_out;

    char* ws = (char*)d_ws;
    unsigned short* A  = (unsigned short*)ws;                    //   262,144 B
    float* d_pos       = (float*)(ws + 262144);                  //     4,096 B
    float* rowsum      = (float*)(ws + 266240);                  //    65,536 B

    prep_kernel<<<128, 256, 0, stream>>>(batch, proxies, labels, A, d_pos, rowsum, out);
    main_kernel<<<NCH, 512, 0, stream>>>(proxies, A, rowsum);
    final_kernel<<<4, 256, 0, stream>>>(rowsum, d_pos, out);
}